// Round 3
// baseline (245.769 us; speedup 1.0000x reference)
//
#include <hip/hip_runtime.h>

// Sparse 3D conv, rulebook (sorted-by-offset) scatter formulation.
// Phase 1: bucket all valid (voxel, out_idx) pairs by kernel offset (27 buckets).
// Phase 2: one block-column per offset; each wave holds that offset's W column
//          in 32 VGPRs (lane = cout) and streams pairs: scalar feature loads
//          (SGPRs), 32 v_fmac_f32, one 64-lane atomicAdd per pair.

#define DOUT 48
#define KS 3
#define CIN 32
#define COUT 64
#define NOFF 27
#define CAP 32768   // max pairs per offset bucket (true max ~25.5k by parity)

// ws layout: int gcnt[32] (128 B), then int2 pairs[NOFF * CAP]  (~7.1 MB total)

__global__ __launch_bounds__(256) void build_rulebook_kernel(
    const int* __restrict__ coors,   // [N,4] (b,z,y,x)
    int*       __restrict__ gcnt,    // [27] zeroed
    int2*      __restrict__ pairs,   // [27][CAP]
    int N)
{
    __shared__ int hist[NOFF];
    __shared__ int base[NOFF];
    const int t = threadIdx.x;
    if (t < NOFF) hist[t] = 0;
    __syncthreads();

    const int vi = blockIdx.x * blockDim.x + t;
    int kzs[2], zos[2], nz = 0;
    int kys[2], yos[2], ny = 0;
    int kxs[2], xos[2], nx = 0;
    int b = 0;
    if (vi < N) {
        b = coors[vi * 4 + 0];
        const int z = coors[vi * 4 + 1];
        const int y = coors[vi * 4 + 2];
        const int x = coors[vi * 4 + 3];
        for (int k = (z + 1) & 1; k < KS; k += 2) {
            int o = (z + 1 - k) >> 1;
            if (o >= 0 && o < DOUT) { kzs[nz] = k; zos[nz] = o; ++nz; }
        }
        for (int k = (y + 1) & 1; k < KS; k += 2) {
            int o = (y + 1 - k) >> 1;
            if (o >= 0 && o < DOUT) { kys[ny] = k; yos[ny] = o; ++ny; }
        }
        for (int k = (x + 1) & 1; k < KS; k += 2) {
            int o = (x + 1 - k) >> 1;
            if (o >= 0 && o < DOUT) { kxs[nx] = k; xos[nx] = o; ++nx; }
        }
        for (int i = 0; i < nz; ++i)
            for (int j = 0; j < ny; ++j)
                for (int k = 0; k < nx; ++k) {
                    int off = (kzs[i] * KS + kys[j]) * KS + kxs[k];
                    atomicAdd(&hist[off], 1);
                }
    }
    __syncthreads();
    if (t < NOFF) {
        base[t] = atomicAdd(&gcnt[t], hist[t]);
        hist[t] = 0;   // reuse as intra-block running position
    }
    __syncthreads();
    if (vi < N) {
        for (int i = 0; i < nz; ++i)
            for (int j = 0; j < ny; ++j)
                for (int k = 0; k < nx; ++k) {
                    int off  = (kzs[i] * KS + kys[j]) * KS + kxs[k];
                    int oidx = (((b * DOUT + zos[i]) * DOUT + yos[j]) * DOUT + xos[k]);
                    int s = base[off] + atomicAdd(&hist[off], 1);
                    if (s < CAP) pairs[off * CAP + s] = make_int2(vi, oidx);
                }
    }
}

__global__ __launch_bounds__(256) void spconv_pairs_kernel(
    const float* __restrict__ feat,   // [N, CIN]
    const float* __restrict__ W,      // [27, CIN, COUT] fp32
    const int*   __restrict__ gcnt,   // [27]
    const int2*  __restrict__ pairs,  // [27][CAP]
    float*       __restrict__ out)    // [B*DOUT^3, COUT] pre-zeroed
{
    const int off  = blockIdx.y;
    const int lane = threadIdx.x & 63;
    const int n    = gcnt[off];

    // This offset's W column, fp32, lane = cout: 32 coalesced loads, once.
    float w[CIN];
#pragma unroll
    for (int c = 0; c < CIN; ++c) w[c] = W[(off * CIN + c) * COUT + lane];

    const int2* pb = pairs + (size_t)off * CAP;
    // Wave-uniform pair index in an SGPR -> pair + feature loads scalarize.
    int p = __builtin_amdgcn_readfirstlane(blockIdx.x * 4 + (threadIdx.x >> 6));
    const int stride = gridDim.x * 4;

    for (; p < n; p += stride) {
        const int2 pr = pb[p];               // uniform addr -> s_load_dwordx2
        const int vi   = __builtin_amdgcn_readfirstlane(pr.x);
        const int oidx = __builtin_amdgcn_readfirstlane(pr.y);
        const float* fp = feat + (size_t)vi * CIN;   // uniform -> s_loads
        float acc = 0.0f;
#pragma unroll
        for (int c = 0; c < CIN; ++c) acc += fp[c] * w[c];   // v_fmac v,s,v
        atomicAdd(&out[(size_t)oidx * COUT + lane], acc);
    }
}

extern "C" void kernel_launch(void* const* d_in, const int* in_sizes, int n_in,
                              void* d_out, int out_size, void* d_ws, size_t ws_size,
                              hipStream_t stream) {
    const float* feat  = (const float*)d_in[0];
    const int*   coors = (const int*)d_in[1];
    const float* W     = (const float*)d_in[3];
    float*       out   = (float*)d_out;

    int*  gcnt  = (int*)d_ws;
    int2* pairs = (int2*)((char*)d_ws + 128);

    const int N = in_sizes[0] / CIN;  // 200000

    // Zero bucket counters + output (harness poisons both with 0xAA).
    hipMemsetAsync(d_ws, 0, 128, stream);
    hipMemsetAsync(d_out, 0, (size_t)out_size * sizeof(float), stream);

    build_rulebook_kernel<<<(N + 255) / 256, 256, 0, stream>>>(coors, gcnt, pairs, N);

    dim3 grid(64, NOFF);
    spconv_pairs_kernel<<<grid, 256, 0, stream>>>(feat, W, gcnt, pairs, out);
}

// Round 4
// 242.282 us; speedup vs baseline: 1.0144x; 1.0144x over previous
//
#include <hip/hip_runtime.h>

// Sparse 3D conv via rulebook + implicit-GEMM (MFMA).
// Phase 0 (prep): zero output (float4), zero bucket counters, pack W into
//                 bf16 MFMA B-fragment layout.
// Phase 1 (rulebook): bucket valid (voxel, out_idx) pairs by kernel offset.
// Phase 2 (pairs): per offset, waves stream 16-pair tiles:
//   lanes 0-15 hold pairs; A-frag gathered straight from global fp32 feat
//   (lane l: row of pair l&15, k-chunk l>>4), cvt->bf16 in-register;
//   4x mfma_f32_16x16x32_bf16 (K=32 = whole Cin); C-frags scatter via
//   16 atomicAdd instrs (4x64B segments each).

#define DOUT 48
#define KS 3
#define CIN 32
#define COUT 64
#define NOFF 27
#define CAP 28672          // max bucket ~25.2k (all-odd parity class) + 20 sigma
#define WPACK_ELEMS (NOFF * 4 * 64 * 8)   // 55296 bf16

typedef __attribute__((ext_vector_type(8))) short bf16x8;
typedef __attribute__((ext_vector_type(4))) float f32x4;

static __device__ __forceinline__ unsigned short f2bf(float x) {
    unsigned u = __float_as_uint(x);
    u += 0x7fffu + ((u >> 16) & 1u);   // RNE
    return (unsigned short)(u >> 16);
}

// ws layout: [0,128)   int gcnt[32]
//            [128, 128 + NOFF*CAP*8)  int2 pairs
//            then bf16 Wpack[WPACK_ELEMS] (16B-aligned)
#define PAIRS_OFF 128
#define WPACK_OFF (PAIRS_OFF + NOFF * CAP * 8)

__global__ __launch_bounds__(256) void prep_kernel(
    const float* __restrict__ W,
    float*       __restrict__ out,
    int*         __restrict__ gcnt,
    unsigned short* __restrict__ Wpack,
    int out_elems, int zero_blocks)
{
    const int bid = blockIdx.x;
    if (bid < zero_blocks) {
        int i = (bid * 256 + threadIdx.x) * 4;
        if (i < out_elems) {
            float4 z = make_float4(0.f, 0.f, 0.f, 0.f);
            *(float4*)(out + i) = z;
        }
        return;
    }
    if (bid == zero_blocks) {
        if (threadIdx.x < 32) gcnt[threadIdx.x] = 0;
        return;
    }
    // W pack: tid -> Wpack[((o*4+f)*64+l)*8 + j] = bf16(W[o][k][cout]),
    // k = (l>>4)*8 + j, cout = f*16 + (l&15).
    int tid = (bid - zero_blocks - 1) * 256 + threadIdx.x;
    if (tid >= WPACK_ELEMS) return;
    int j = tid & 7;
    int l = (tid >> 3) & 63;
    int f = (tid >> 9) & 3;
    int o = tid >> 11;
    int k    = ((l >> 4) << 3) + j;
    int cout = (f << 4) + (l & 15);
    Wpack[tid] = f2bf(W[(o * CIN + k) * COUT + cout]);
}

__global__ __launch_bounds__(256) void build_rulebook_kernel(
    const int* __restrict__ coors,   // [N,4] (b,z,y,x)
    int*       __restrict__ gcnt,    // [27] zeroed
    int2*      __restrict__ pairs,   // [27][CAP]
    int N)
{
    __shared__ int hist[NOFF];
    __shared__ int base[NOFF];
    const int t = threadIdx.x;
    if (t < NOFF) hist[t] = 0;
    __syncthreads();

    const int vi = blockIdx.x * blockDim.x + t;
    int kzs[2], zos[2], nz = 0;
    int kys[2], yos[2], ny = 0;
    int kxs[2], xos[2], nx = 0;
    int b = 0;
    if (vi < N) {
        b = coors[vi * 4 + 0];
        const int z = coors[vi * 4 + 1];
        const int y = coors[vi * 4 + 2];
        const int x = coors[vi * 4 + 3];
        for (int k = (z + 1) & 1; k < KS; k += 2) {
            int o = (z + 1 - k) >> 1;
            if (o >= 0 && o < DOUT) { kzs[nz] = k; zos[nz] = o; ++nz; }
        }
        for (int k = (y + 1) & 1; k < KS; k += 2) {
            int o = (y + 1 - k) >> 1;
            if (o >= 0 && o < DOUT) { kys[ny] = k; yos[ny] = o; ++ny; }
        }
        for (int k = (x + 1) & 1; k < KS; k += 2) {
            int o = (x + 1 - k) >> 1;
            if (o >= 0 && o < DOUT) { kxs[nx] = k; xos[nx] = o; ++nx; }
        }
        for (int i = 0; i < nz; ++i)
            for (int j = 0; j < ny; ++j)
                for (int k = 0; k < nx; ++k) {
                    int off = (kzs[i] * KS + kys[j]) * KS + kxs[k];
                    atomicAdd(&hist[off], 1);
                }
    }
    __syncthreads();
    if (t < NOFF) {
        base[t] = atomicAdd(&gcnt[t], hist[t]);
        hist[t] = 0;   // reuse as intra-block running position
    }
    __syncthreads();
    if (vi < N) {
        for (int i = 0; i < nz; ++i)
            for (int j = 0; j < ny; ++j)
                for (int k = 0; k < nx; ++k) {
                    int off  = (kzs[i] * KS + kys[j]) * KS + kxs[k];
                    int oidx = (((b * DOUT + zos[i]) * DOUT + yos[j]) * DOUT + xos[k]);
                    int s = base[off] + atomicAdd(&hist[off], 1);
                    if (s < CAP) pairs[off * CAP + s] = make_int2(vi, oidx);
                }
    }
}

__global__ __launch_bounds__(256) void spconv_mfma_kernel(
    const float* __restrict__ feat,   // [N, CIN] fp32
    const int*   __restrict__ gcnt,   // [27]
    const int2*  __restrict__ pairs,  // [27][CAP]
    const unsigned short* __restrict__ Wpack,  // bf16 B-frag layout
    float*       __restrict__ out)    // [B*DOUT^3, COUT] pre-zeroed
{
    const int off  = blockIdx.y;
    const int lane = threadIdx.x & 63;
    const int col   = lane & 15;   // n within 16-block / pair slot for loads
    const int khalf = lane >> 4;   // 0..3 -> k-chunk of 8

    int n = gcnt[off];
    if (n > CAP) n = CAP;

    // B-fragments for this offset: 4 couts-of-16 blocks, coalesced dwordx4.
    const bf16x8* wp = (const bf16x8*)Wpack + (off * 4) * 64 + lane;
    bf16x8 bfrag0 = wp[0];
    bf16x8 bfrag1 = wp[64];
    bf16x8 bfrag2 = wp[128];
    bf16x8 bfrag3 = wp[192];

    const int2* pb = pairs + (size_t)off * CAP;
    const int wid = blockIdx.x * 4 + (threadIdx.x >> 6);
    const int wstride = gridDim.x * 4;

    for (int base = wid * 16; base < n; base += wstride * 16) {
        const int pidx = base + col;
        const bool valid = pidx < n;
        int2 pr = make_int2(0, 0);
        if (valid) pr = pb[pidx];       // lane l holds pair (l&15)

        // Gather A: 8 fp32 of feat row pr.x, k-chunk khalf -> bf16 frag.
        const float* fp = feat + (size_t)pr.x * CIN + (khalf << 3);
        const float4 a0 = *(const float4*)fp;
        const float4 a1 = *(const float4*)(fp + 4);
        bf16x8 afrag;
        afrag[0] = (short)f2bf(a0.x); afrag[1] = (short)f2bf(a0.y);
        afrag[2] = (short)f2bf(a0.z); afrag[3] = (short)f2bf(a0.w);
        afrag[4] = (short)f2bf(a1.x); afrag[5] = (short)f2bf(a1.y);
        afrag[6] = (short)f2bf(a1.z); afrag[7] = (short)f2bf(a1.w);
        if (!valid) afrag = (bf16x8)0;  // zero rows for tail -> adds 0.0

        const f32x4 z4 = {0.f, 0.f, 0.f, 0.f};
        f32x4 acc0 = __builtin_amdgcn_mfma_f32_16x16x32_bf16(afrag, bfrag0, z4, 0, 0, 0);
        f32x4 acc1 = __builtin_amdgcn_mfma_f32_16x16x32_bf16(afrag, bfrag1, z4, 0, 0, 0);
        f32x4 acc2 = __builtin_amdgcn_mfma_f32_16x16x32_bf16(afrag, bfrag2, z4, 0, 0, 0);
        f32x4 acc3 = __builtin_amdgcn_mfma_f32_16x16x32_bf16(afrag, bfrag3, z4, 0, 0, 0);

        // C layout: col = lane&15, row m = khalf*4 + r. Pair m's out idx lives
        // in lane m (m < 16) -> bpermute.
#pragma unroll
        for (int r = 0; r < 4; ++r) {
            const int m = (khalf << 2) + r;
            const int oidx = __builtin_amdgcn_ds_bpermute(m << 2, pr.y);
            float* op = out + (size_t)oidx * COUT + col;
            atomicAdd(op +  0, acc0[r]);
            atomicAdd(op + 16, acc1[r]);
            atomicAdd(op + 32, acc2[r]);
            atomicAdd(op + 48, acc3[r]);
        }
    }
}

extern "C" void kernel_launch(void* const* d_in, const int* in_sizes, int n_in,
                              void* d_out, int out_size, void* d_ws, size_t ws_size,
                              hipStream_t stream) {
    const float* feat  = (const float*)d_in[0];
    const int*   coors = (const int*)d_in[1];
    const float* W     = (const float*)d_in[3];
    float*       out   = (float*)d_out;

    int*  gcnt  = (int*)d_ws;
    int2* pairs = (int2*)((char*)d_ws + PAIRS_OFF);
    unsigned short* Wpack = (unsigned short*)((char*)d_ws + WPACK_OFF);

    const int N = in_sizes[0] / CIN;  // 200000

    // Prep: zero out + gcnt, pack W (replaces 56.6MB hipMemsetAsync, ~70us).
    const int zero_blocks = (out_size + 1023) / 1024;
    const int wpack_blocks = (WPACK_ELEMS + 255) / 256;
    prep_kernel<<<zero_blocks + 1 + wpack_blocks, 256, 0, stream>>>(
        W, out, gcnt, Wpack, out_size, zero_blocks);

    build_rulebook_kernel<<<(N + 255) / 256, 256, 0, stream>>>(coors, gcnt, pairs, N);

    dim3 grid(64, NOFF);
    spconv_mfma_kernel<<<grid, 256, 0, stream>>>(feat, gcnt, pairs, Wpack, out);
}